// Round 7
// baseline (280.674 us; speedup 1.0000x reference)
//
#include <hip/hip_runtime.h>

static constexpr int NCOL = 4096;            // last-dim size (fixed by problem)
static constexpr int THREADS = 256;          // 4 waves/block
static constexpr int BLOCKS = 1024;          // 8192 rows / 8 rows-per-block
static constexpr int RPB = 8;                // rows per block

typedef float v4f __attribute__((ext_vector_type(4)));  // for nontemporal stores

// y must be computed by the same inlined expression in rowstats and output
__device__ __forceinline__ float norm_y(float x, float mu, float inv_std,
                                        float g, float b) {
    float xn = (x - mu) * inv_std;
    return xn * g + b;
}

__device__ __forceinline__ float wave_max_f(float m) {
    #pragma unroll
    for (int off = 32; off > 0; off >>= 1)
        m = fmaxf(m, __shfl_down(m, off));
    return m;
}

// block-level max over 4 waves; returns value to ALL threads
__device__ __forceinline__ float block_max_f(float m, float* sred) {
    const int lane = threadIdx.x & 63, w = threadIdx.x >> 6;
    m = wave_max_f(m);
    if (lane == 0) sred[w] = m;
    __syncthreads();
    float r = fmaxf(fmaxf(sred[0], sred[1]), fmaxf(sred[2], sred[3]));
    __syncthreads();
    return r;
}

// ---------------- kernel 1: per-block partial amax(|x|) ----------------
// each block scans its own 8 contiguous rows (128 KB), perfectly coalesced
__global__ void __launch_bounds__(THREADS) k_amax(const float* __restrict__ x,
                                                  float* __restrict__ pA) {
    const long long base = (long long)blockIdx.x * RPB * NCOL;
    const int t = threadIdx.x;
    float m = 0.0f;
    #pragma unroll
    for (int j = 0; j < 32; ++j) {
        const float4 v = *reinterpret_cast<const float4*>(x + base + (j * THREADS + t) * 4);
        m = fmaxf(m, fmaxf(fmaxf(fabsf(v.x), fabsf(v.y)),
                           fmaxf(fabsf(v.z), fabsf(v.w))));
    }
    __shared__ float sred[THREADS / 64];
    m = block_max_f(m, sred);
    if (t == 0) pA[blockIdx.x] = m;
}

// ---------------- kernel 2: per-row stats + per-block amax(|y|) ----------------
__global__ void __launch_bounds__(THREADS) k_rowstats(
        const float* __restrict__ x,
        const float* __restrict__ gamma,
        const float* __restrict__ beta,
        const float* __restrict__ pA,    // [BLOCKS] partials from k_amax
        float* __restrict__ pY,          // [BLOCKS] partial amax|y| out
        float* __restrict__ mu_arr,
        float* __restrict__ is_arr) {
    const int t = threadIdx.x;
    const int lane = t & 63, w = t >> 6;
    __shared__ float sred[THREADS / 64];
    __shared__ int sredi[2 * THREADS / 64];

    // every block redundantly reduces the 1024 partials (L2-broadcast, ~4KB)
    const float4 pv = *reinterpret_cast<const float4*>(pA + t * 4);
    float am = block_max_f(fmaxf(fmaxf(pv.x, pv.y), fmaxf(pv.z, pv.w)), sred);
    const float scale_in = fmaxf(am / 127.0f, 1e-8f);
    const float r_in = 1.0f / scale_in;     // one IEEE division; loops multiply

    // gamma/beta once per block, registers across the 8 rows
    float4 gf[4], bf[4];
    #pragma unroll
    for (int j = 0; j < 4; ++j) {
        gf[j] = *reinterpret_cast<const float4*>(gamma + j * 1024 + t * 4);
        bf[j] = *reinterpret_cast<const float4*>(beta  + j * 1024 + t * 4);
    }

    const long long base = (long long)blockIdx.x * RPB * NCOL;
    float ymax = 0.0f;
    #pragma unroll
    for (int r = 0; r < RPB; ++r) {
        const float* xr = x + base + r * NCOL;
        float xs[16];
        #pragma unroll
        for (int j = 0; j < 4; ++j) {
            const float4 v = *reinterpret_cast<const float4*>(xr + j * 1024 + t * 4);
            xs[4 * j + 0] = v.x; xs[4 * j + 1] = v.y;
            xs[4 * j + 2] = v.z; xs[4 * j + 3] = v.w;
        }
        // Sx exact (|Sx| <= 127*4096 < 2^24), Sxx exact in int32
        int sx = 0, sxx = 0;
        #pragma unroll
        for (int e = 0; e < 16; ++e) {
            float q = rintf(xs[e] * r_in);
            q = fminf(fmaxf(q, -127.0f), 127.0f);
            const int qi = (int)q;
            sx += qi;
            sxx += qi * qi;
        }
        #pragma unroll
        for (int off = 32; off > 0; off >>= 1) {
            sx  += __shfl_down(sx, off);
            sxx += __shfl_down(sxx, off);
        }
        if (lane == 0) { sredi[w] = sx; sredi[4 + w] = sxx; }
        __syncthreads();
        const int Sx  = sredi[0] + sredi[1] + sredi[2] + sredi[3];
        const int Sxx = sredi[4] + sredi[5] + sredi[6] + sredi[7];
        __syncthreads();   // protect sredi before next row overwrites

        // moments (all threads redundantly; pow2 divides are exact)
        const float Ex  = (float)Sx * scale_in;
        const float Ex2 = (float)Sxx * (scale_in * scale_in);
        const float mu  = Ex * (1.0f / NCOL);
        const float var = fmaxf(Ex2 * (1.0f / NCOL) - mu * mu, 0.0f);
        const int d = (int)fminf(fmaxf(rintf(var), 1.0f), 65535.0f);

        // exact replication of the reference LUT integer sqrt (rounded)
        const int msb = 31 - __clz(d);
        const int sh = 7 - (msb >> 1);
        const int dnorm = d << (sh * 2);
        const int lut = (dnorm >> 8) & 255;
        const int v2 = lut * 256 + 128;
        int mant = (int)__fsqrt_rn((float)v2);
        while (mant * mant > v2) --mant;
        while ((mant + 1) * (mant + 1) <= v2) ++mant;
        const int qf = mant >> sh;
        const int std_i = (d > qf * qf + qf) ? qf + 1 : qf;
        const float inv_std = 1.0f / fmaxf((float)std_i, 1e-5f);

        if (t == 0) {
            mu_arr[blockIdx.x * RPB + r] = mu;
            is_arr[blockIdx.x * RPB + r] = inv_std;
        }

        #pragma unroll
        for (int j = 0; j < 4; ++j) {
            ymax = fmaxf(ymax, fabsf(norm_y(xs[4*j+0], mu, inv_std, gf[j].x, bf[j].x)));
            ymax = fmaxf(ymax, fabsf(norm_y(xs[4*j+1], mu, inv_std, gf[j].y, bf[j].y)));
            ymax = fmaxf(ymax, fabsf(norm_y(xs[4*j+2], mu, inv_std, gf[j].z, bf[j].z)));
            ymax = fmaxf(ymax, fabsf(norm_y(xs[4*j+3], mu, inv_std, gf[j].w, bf[j].w)));
        }
    }
    ymax = block_max_f(ymax, sred);
    if (t == 0) pY[blockIdx.x] = ymax;
}

// ---------------- kernel 3: normalize + requantize + NT store ----------------
__global__ void __launch_bounds__(THREADS) k_output(
        const float* __restrict__ x,
        const float* __restrict__ gamma,
        const float* __restrict__ beta,
        const float* __restrict__ mu_arr,
        const float* __restrict__ is_arr,
        const float* __restrict__ pY,    // [BLOCKS] partials from k_rowstats
        float* __restrict__ out) {
    const int t = threadIdx.x;
    __shared__ float sred[THREADS / 64];

    const float4 pv = *reinterpret_cast<const float4*>(pY + t * 4);
    float ym = block_max_f(fmaxf(fmaxf(pv.x, pv.y), fmaxf(pv.z, pv.w)), sred);
    const float scale_out = fmaxf(ym / 127.0f, 1e-8f);
    const float r_out = 1.0f / scale_out;   // one IEEE division; loops multiply

    float4 gf[4], bf[4];
    #pragma unroll
    for (int j = 0; j < 4; ++j) {
        gf[j] = *reinterpret_cast<const float4*>(gamma + j * 1024 + t * 4);
        bf[j] = *reinterpret_cast<const float4*>(beta  + j * 1024 + t * 4);
    }

    const long long base = (long long)blockIdx.x * RPB * NCOL;
    #pragma unroll
    for (int r = 0; r < RPB; ++r) {
        const float mu = mu_arr[blockIdx.x * RPB + r];
        const float inv_std = is_arr[blockIdx.x * RPB + r];
        const float* xr = x + base + r * NCOL;
        float* orow = out + base + r * NCOL;
        #pragma unroll
        for (int j = 0; j < 4; ++j) {
            const float4 v = *reinterpret_cast<const float4*>(xr + j * 1024 + t * 4);
            v4f o;
            {
                float q = fminf(fmaxf(rintf(norm_y(v.x, mu, inv_std, gf[j].x, bf[j].x) * r_out), -127.0f), 127.0f);
                o.x = q * scale_out;
            }
            {
                float q = fminf(fmaxf(rintf(norm_y(v.y, mu, inv_std, gf[j].y, bf[j].y) * r_out), -127.0f), 127.0f);
                o.y = q * scale_out;
            }
            {
                float q = fminf(fmaxf(rintf(norm_y(v.z, mu, inv_std, gf[j].z, bf[j].z) * r_out), -127.0f), 127.0f);
                o.z = q * scale_out;
            }
            {
                float q = fminf(fmaxf(rintf(norm_y(v.w, mu, inv_std, gf[j].w, bf[j].w) * r_out), -127.0f), 127.0f);
                o.w = q * scale_out;
            }
            // out is never re-read: keep it out of L2/L3 so x stays resident
            __builtin_nontemporal_store(o, reinterpret_cast<v4f*>(orow + j * 1024 + t * 4));
        }
    }
}

extern "C" void kernel_launch(void* const* d_in, const int* in_sizes, int n_in,
                              void* d_out, int out_size, void* d_ws, size_t ws_size,
                              hipStream_t stream) {
    const float* x     = (const float*)d_in[0];
    const float* gamma = (const float*)d_in[1];
    const float* beta  = (const float*)d_in[2];
    float* out = (float*)d_out;

    const int rows = in_sizes[0] > 0 ? (int)((long long)in_sizes[0] / NCOL) : BLOCKS * RPB;

    // workspace (floats): pA[1024], pY[1024], mu[rows], is[rows]
    float* ws = (float*)d_ws;
    float* pA     = ws;
    float* pY     = ws + BLOCKS;
    float* mu_arr = ws + 2 * BLOCKS;
    float* is_arr = mu_arr + rows;

    k_amax<<<BLOCKS, THREADS, 0, stream>>>(x, pA);
    k_rowstats<<<BLOCKS, THREADS, 0, stream>>>(x, gamma, beta, pA, pY,
                                               mu_arr, is_arr);
    k_output<<<BLOCKS, THREADS, 0, stream>>>(x, gamma, beta, mu_arr, is_arr,
                                             pY, out);
}